// Round 4
// baseline (241.151 us; speedup 1.0000x reference)
//
#include <hip/hip_runtime.h>
#include <stdint.h>

// RNN: h_t = tanh(x_t W_ih^T + b_ih + b_hh + h_{t-1} W_hh^T)
// out[b,t] = W_fc . h_t + b_fc ;  hidden = h_T
// B=8192, T=512, I=H=7, O=1. fp32 I/O.
//
// 8 lanes per chain (lane k owns h-row k; lane 7 dummy). 8192 chains.
// R3 -> R4 changes:
//  - out-projection moved OUT of the serial step loop: save own-lane hk per
//    step, post-chunk 3-stage DPP butterfly (xor1, xor2, half-mirror) sums
//    wfc_k*hk across the 8-lane group. Pure ILP filler, off critical path.
//  - 1024 blocks x 64 threads (was 256x256): even block->CU distribution
//    (4 single-wave blocks per CU), full VGPR budget for the double buffer.
//  - serial loop body now: 9-op dot + 5-op tanh + 8 DPP broadcast only.

#define B_TOTAL 8192
#define T_STEPS 512

#define DPP_QUAD0 0x00        // quad_perm [0,0,0,0]
#define DPP_QUAD1 0x55        // quad_perm [1,1,1,1]
#define DPP_QUAD2 0xAA        // quad_perm [2,2,2,2]
#define DPP_QUAD3 0xFF        // quad_perm [3,3,3,3]
#define DPP_XOR1  0xB1        // quad_perm [1,0,3,2]
#define DPP_XOR2  0x4E        // quad_perm [2,3,0,1]
#define DPP_HALF_MIRROR 0x141 // mirror within 8-lane half-row

template <int CTRL>
__device__ __forceinline__ float dpp_mov(float v) {
    int r = __builtin_amdgcn_update_dpp(0, __float_as_int(v), CTRL, 0xF, 0xF, true);
    return __int_as_float(r);
}

__device__ __forceinline__ float tanh_fast(float a) {
    // tanh(a) = 1 - 2/(1+e^{2a});  e^{2a} = exp2(a * 2*log2(e))
    float e = __builtin_amdgcn_exp2f(a * 2.8853900817779268f);
    float r = __builtin_amdgcn_rcpf(e + 1.0f);
    return __builtin_fmaf(-2.0f, r, 1.0f);
}

__global__ __launch_bounds__(64, 1) void rnn_kernel(
    const float* __restrict__ x,    // [B, T, I]
    const float* __restrict__ Wih,  // [H, I]
    const float* __restrict__ Whh,  // [H, H]
    const float* __restrict__ bih,  // [H]
    const float* __restrict__ bhh,  // [H]
    const float* __restrict__ Wfc,  // [1, H]
    const float* __restrict__ bfc,  // [1]
    float* __restrict__ out)        // [B*T] out, then [B*H] hidden
{
    const int tid  = threadIdx.x;
    const int k    = tid & 7;                 // h-row owned by this lane (7=dummy)
    const int b    = blockIdx.x * 8 + (tid >> 3);
    const int quad = (tid >> 2) & 1;          // quad parity within 8-lane group

    // ---- load-time weight permutation for the recurrent dot ----------------
    // quad0 lane row k: a_j=h_j,     b_j=h_{4+j} -> wa[j]=W[k][j],   wb[j]=W[k][4+j]
    // quad1 lane row k: a_j=h_{4+j}, b_j=h_j     -> wa[j]=W[k][4+j], wb[j]=W[k][j]
    float wih[7];
    float wa[4], wb[4];
    float bias = 0.0f, wfc_own = 0.0f;
    {
        float whh_row[8];
        #pragma unroll
        for (int i = 0; i < 8; ++i) whh_row[i] = 0.0f;
        if (k < 7) {
            #pragma unroll
            for (int i = 0; i < 7; ++i) {
                wih[i] = Wih[k * 7 + i];
                whh_row[i] = Whh[k * 7 + i];
            }
            bias = bih[k] + bhh[k];
            wfc_own = Wfc[k];
        } else {
            #pragma unroll
            for (int i = 0; i < 7; ++i) wih[i] = 0.0f;
        }
        #pragma unroll
        for (int j = 0; j < 4; ++j) {
            wa[j] = quad ? whh_row[4 + j] : whh_row[j];
            wb[j] = quad ? whh_row[j]     : whh_row[4 + j];
        }
    }
    const float bfcv = bfc[0];

    // x row: 512*7 = 3584 floats = 896 float4 per chain
    const float4* xrow = (const float4*)(x + (size_t)b * (T_STEPS * 7));
    float* outp = out + (size_t)b * T_STEPS;

    // h state as (a0..a3, b0..b3); h=0 initially
    float a0 = 0.f, a1 = 0.f, a2 = 0.f, a3 = 0.f;
    float b0 = 0.f, b1 = 0.f, b2 = 0.f, b3 = 0.f;

    float4 bufA[14], bufB[14];   // 8 steps * 7 inputs = 56 floats per chunk
    #pragma unroll
    for (int i = 0; i < 14; ++i) bufA[i] = xrow[i];

    auto process = [&](const float4 (&buf)[14], int c) {
        float xv[56];
        #pragma unroll
        for (int i = 0; i < 14; ++i) {   // SSA renaming only (buf dead after)
            xv[4 * i + 0] = buf[i].x; xv[4 * i + 1] = buf[i].y;
            xv[4 * i + 2] = buf[i].z; xv[4 * i + 3] = buf[i].w;
        }
        // Input projection for all 8 steps (independent of h -> ILP filler)
        float u[8];
        #pragma unroll
        for (int s = 0; s < 8; ++s) {
            const float* xs = &xv[s * 7];
            float p01 = __builtin_fmaf(wih[1], xs[1], wih[0] * xs[0]);
            float p23 = __builtin_fmaf(wih[3], xs[3], wih[2] * xs[2]);
            float p45 = __builtin_fmaf(wih[5], xs[5], wih[4] * xs[4]);
            float p6b = __builtin_fmaf(wih[6], xs[6], bias);
            u[s] = (p01 + p23) + (p45 + p6b);
        }
        // Serial recurrence: dot + tanh + DPP broadcast ONLY
        float hs[8];
        #pragma unroll
        for (int s = 0; s < 8; ++s) {
            float p0 = __builtin_fmaf(wa[0], a0, u[s]);
            float p1 = __builtin_fmaf(wa[2], a2, wa[1] * a1);
            float p2 = __builtin_fmaf(wb[0], b0, wa[3] * a3);
            float p3 = __builtin_fmaf(wb[2], b2, wb[1] * b1);
            float p4 = wb[3] * b3;
            float acc = (p0 + p1) + (p2 + (p3 + p4));
            float hk = tanh_fast(acc);
            hs[s] = hk;                       // own-lane h for post-loop out-proj
            a0 = dpp_mov<DPP_QUAD0>(hk);
            a1 = dpp_mov<DPP_QUAD1>(hk);
            a2 = dpp_mov<DPP_QUAD2>(hk);
            a3 = dpp_mov<DPP_QUAD3>(hk);
            b0 = dpp_mov<DPP_HALF_MIRROR>(a0);
            b1 = dpp_mov<DPP_HALF_MIRROR>(a1);
            b2 = dpp_mov<DPP_HALF_MIRROR>(a2);
            b3 = dpp_mov<DPP_HALF_MIRROR>(a3);
        }
        // Out-projection: butterfly-sum wfc_k*hk over the 8-lane group.
        // After xor1+xor2 all lanes of a quad hold the quad sum, so the
        // half-mirror (lane -> 7-lane, other quad) completes the 8-sum.
        float o[8];
        #pragma unroll
        for (int s = 0; s < 8; ++s) {
            float v = wfc_own * hs[s];
            v += dpp_mov<DPP_XOR1>(v);
            v += dpp_mov<DPP_XOR2>(v);
            v += dpp_mov<DPP_HALF_MIRROR>(v);
            o[s] = v + bfcv;
        }
        if (k == 7) {
            *(float4*)(outp + c * 8 + 0) = make_float4(o[0], o[1], o[2], o[3]);
            *(float4*)(outp + c * 8 + 4) = make_float4(o[4], o[5], o[6], o[7]);
        }
    };

    for (int c = 0; c < 64; c += 2) {
        #pragma unroll
        for (int i = 0; i < 14; ++i) bufB[i] = xrow[(c + 1) * 14 + i];
        process(bufA, c);
        if (c + 2 < 64) {
            #pragma unroll
            for (int i = 0; i < 14; ++i) bufA[i] = xrow[(c + 2) * 14 + i];
        }
        process(bufB, c + 1);
    }

    // hidden state h_T: lane k's own value is a_{k&3} (both quads)
    if (k < 7) {
        int kk = k & 3;
        float hv = (kk == 0) ? a0 : (kk == 1) ? a1 : (kk == 2) ? a2 : a3;
        out[(size_t)B_TOTAL * T_STEPS + (size_t)b * 7 + k] = hv;
    }
}

extern "C" void kernel_launch(void* const* d_in, const int* in_sizes, int n_in,
                              void* d_out, int out_size, void* d_ws, size_t ws_size,
                              hipStream_t stream) {
    const float* x   = (const float*)d_in[0];
    const float* Wih = (const float*)d_in[1];
    const float* Whh = (const float*)d_in[2];
    const float* bih = (const float*)d_in[3];
    const float* bhh = (const float*)d_in[4];
    const float* Wfc = (const float*)d_in[5];
    const float* bfc = (const float*)d_in[6];
    float* out = (float*)d_out;

    // 8192 chains * 8 lanes = 65536 threads; 64/block -> 1024 single-wave
    // blocks -> 4 blocks/CU, even distribution, 1 wave/SIMD.
    rnn_kernel<<<dim3(B_TOTAL / 8), dim3(64), 0, stream>>>(
        x, Wih, Whh, bih, bhh, Wfc, bfc, out);
}

// Round 5
// 230.483 us; speedup vs baseline: 1.0463x; 1.0463x over previous
//
#include <hip/hip_runtime.h>
#include <stdint.h>

// RNN: h_t = tanh(x_t W_ih^T + b_ih + b_hh + h_{t-1} W_hh^T)
// out[b,t] = W_fc . h_t + b_fc ;  hidden = h_T.  B=8192, T=512, I=H=7. fp32.
//
// R5: producer-consumer wave specialization. Block = 128 thr = 2 waves,
// 8 chains/block. W0 = serial recurrence only (verified R3 DPP math).
// W1 = x prefetch + input-proj u -> LDS + out-proj butterfly + stores.
// Raw s_barrier + lgkmcnt(0) (NO vmcnt drain) so W1's global prefetch
// stays in flight across barriers. 1024 blocks -> 2 waves/SIMD TLP.

#define B_TOTAL 8192
#define T_STEPS 512

#define DPP_QUAD0 0x00        // quad_perm [0,0,0,0]
#define DPP_QUAD1 0x55        // quad_perm [1,1,1,1]
#define DPP_QUAD2 0xAA        // quad_perm [2,2,2,2]
#define DPP_QUAD3 0xFF        // quad_perm [3,3,3,3]
#define DPP_XOR1  0xB1        // quad_perm [1,0,3,2]
#define DPP_XOR2  0x4E        // quad_perm [2,3,0,1]
#define DPP_HM    0x141       // row_half_mirror

template <int CTRL>
__device__ __forceinline__ float dpp_mov(float v) {
    int s = __float_as_int(v);
    // old = src: bound_ctrl=1 + full masks -> old never used, no extra mov
    return __int_as_float(__builtin_amdgcn_update_dpp(s, s, CTRL, 0xF, 0xF, true));
}

__device__ __forceinline__ float tanh_fast(float a) {
    float e = __builtin_amdgcn_exp2f(a * 2.8853900817779268f);
    float r = __builtin_amdgcn_rcpf(e + 1.0f);
    return __builtin_fmaf(-2.0f, r, 1.0f);
}

// Raw barrier: waits LDS ops only (lgkmcnt), leaves global loads in flight.
// Memory clobbers pin LDS/global ops inside their iteration.
__device__ __forceinline__ void block_sync() {
    __asm__ volatile("" ::: "memory");
    __asm__ volatile("s_waitcnt lgkmcnt(0)" ::: "memory");
    __builtin_amdgcn_s_barrier();
    __asm__ volatile("" ::: "memory");
}

__device__ __forceinline__ float f4c(const float4& v, int c) {
    switch (c & 3) { case 0: return v.x; case 1: return v.y;
                     case 2: return v.z; default: return v.w; }
}

__global__ __launch_bounds__(128, 2) void rnn_kernel(
    const float* __restrict__ x,    // [B, T, I]
    const float* __restrict__ Wih,  // [H, I]
    const float* __restrict__ Whh,  // [H, H]
    const float* __restrict__ bih,  // [H]
    const float* __restrict__ bhh,  // [H]
    const float* __restrict__ Wfc,  // [1, H]
    const float* __restrict__ bfc,  // [1]
    float* __restrict__ out)        // [B*T] out, then [B*H] hidden
{
    const int tid  = threadIdx.x;
    const int wid  = tid >> 6;            // 0 = serial wave, 1 = helper wave
    const int lane = tid & 63;
    const int k    = lane & 7;            // h-row (7 = dummy)
    const int g    = lane >> 3;           // chain-in-block 0..7
    const int b    = blockIdx.x * 8 + g;
    const int quad = (lane >> 2) & 1;     // quad parity within 8-lane group

    __shared__ float uBuf[2][8][8][8];    // [par][g][k][s]  (b128/lane)
    __shared__ float hBuf[2][8][8][8];    // [par][s][g][k]  (stride-1, no conflicts)

    const float bfcv = bfc[0];
    float* outp = out + (size_t)b * T_STEPS;

    if (wid == 0) {
        // ================= W0: serial recurrence =================
        float wa[4], wb[4];
        {
            float whh_row[8];
            #pragma unroll
            for (int i = 0; i < 8; ++i) whh_row[i] = 0.0f;
            if (k < 7) {
                #pragma unroll
                for (int i = 0; i < 7; ++i) whh_row[i] = Whh[k * 7 + i];
            }
            #pragma unroll
            for (int j = 0; j < 4; ++j) {
                wa[j] = quad ? whh_row[4 + j] : whh_row[j];
                wb[j] = quad ? whh_row[j]     : whh_row[4 + j];
            }
        }
        float a0 = 0.f, a1 = 0.f, a2 = 0.f, a3 = 0.f;
        float b0 = 0.f, b1 = 0.f, b2 = 0.f, b3 = 0.f;

        auto w0_chunk = [&](int c) {
            const float4* up = (const float4*)&uBuf[c & 1][g][k][0];
            float4 u03 = up[0], u47 = up[1];
            float us[8] = { u03.x, u03.y, u03.z, u03.w,
                            u47.x, u47.y, u47.z, u47.w };
            #pragma unroll
            for (int s = 0; s < 8; ++s) {
                float p0 = __builtin_fmaf(wa[0], a0, us[s]);
                float p1 = __builtin_fmaf(wa[2], a2, wa[1] * a1);
                float p2 = __builtin_fmaf(wb[0], b0, wa[3] * a3);
                float p3 = __builtin_fmaf(wb[2], b2, wb[1] * b1);
                float p4 = wb[3] * b3;
                float acc = (p0 + p1) + (p2 + (p3 + p4));
                float hk = tanh_fast(acc);
                hBuf[c & 1][s][g][k] = hk;           // for W1's out-proj
                a0 = dpp_mov<DPP_QUAD0>(hk);
                a1 = dpp_mov<DPP_QUAD1>(hk);
                a2 = dpp_mov<DPP_QUAD2>(hk);
                a3 = dpp_mov<DPP_QUAD3>(hk);
                b0 = dpp_mov<DPP_HM>(a0);
                b1 = dpp_mov<DPP_HM>(a1);
                b2 = dpp_mov<DPP_HM>(a2);
                b3 = dpp_mov<DPP_HM>(a3);
            }
        };

        block_sync();                                 // match W1 preloop sync
        for (int c = 0; c < 64; c += 2) {
            w0_chunk(c);
            block_sync();
            w0_chunk(c + 1);
            block_sync();
        }
        // hidden h_T: lane k's own value is a_{k&3} (both quads)
        if (k < 7) {
            int kk = k & 3;
            float hv = (kk == 0) ? a0 : (kk == 1) ? a1 : (kk == 2) ? a2 : a3;
            out[(size_t)B_TOTAL * T_STEPS + (size_t)b * 7 + k] = hv;
        }
    } else {
        // ================= W1: loads, u, out-proj, stores =================
        float wih[7];
        float bias = 0.0f, wfc_own = 0.0f;
        if (k < 7) {
            #pragma unroll
            for (int i = 0; i < 7; ++i) wih[i] = Wih[k * 7 + i];
            bias = bih[k] + bhh[k];
            wfc_own = Wfc[k];
        } else {
            #pragma unroll
            for (int i = 0; i < 7; ++i) wih[i] = 0.0f;
        }

        const float4* xrow = (const float4*)(x + (size_t)b * (T_STEPS * 7));
        float4 bufA[14], bufB[14];

        auto w1_load = [&](float4 (&buf)[14], int ch) {
            const float4* src = xrow + ch * 14;
            #pragma unroll
            for (int i = 0; i < 14; ++i) buf[i] = src[i];
        };
        auto w1_u = [&](const float4 (&buf)[14], int cn) {
            float us[8];
            #pragma unroll
            for (int s = 0; s < 8; ++s) {
                float acc = bias;
                #pragma unroll
                for (int i = 0; i < 7; ++i)
                    acc = __builtin_fmaf(wih[i], f4c(buf[(s * 7 + i) >> 2], s * 7 + i), acc);
                us[s] = acc;
            }
            float4* dst = (float4*)&uBuf[cn & 1][g][k][0];
            dst[0] = make_float4(us[0], us[1], us[2], us[3]);
            dst[1] = make_float4(us[4], us[5], us[6], us[7]);
        };
        auto w1_fly = [&](int cp) {
            float hs[8];
            #pragma unroll
            for (int s = 0; s < 8; ++s) hs[s] = hBuf[cp & 1][s][g][k];
            float o[8];
            #pragma unroll
            for (int s = 0; s < 8; ++s) {
                float v = wfc_own * hs[s];
                v += dpp_mov<DPP_XOR1>(v);
                v += dpp_mov<DPP_XOR2>(v);
                v += dpp_mov<DPP_HM>(v);
                o[s] = v + bfcv;
            }
            if (k == 7) {
                *(float4*)(outp + cp * 8 + 0) = make_float4(o[0], o[1], o[2], o[3]);
                *(float4*)(outp + cp * 8 + 4) = make_float4(o[4], o[5], o[6], o[7]);
            }
        };

        // Preloop: chunk0->A (consumed now), chunk1->B, chunk2->A
        w1_load(bufA, 0);
        w1_load(bufB, 1);
        w1_u(bufA, 0);
        w1_load(bufA, 2);
        block_sync();

        for (int c = 0; c < 64; c += 2) {
            // even body: consume bufB (chunk c+1), reload with chunk c+3
            w1_u(bufB, c + 1);
            if (c + 3 < 64) w1_load(bufB, c + 3);
            if (c > 0) w1_fly(c - 1);
            block_sync();
            // odd body: consume bufA (chunk c+2), reload with chunk c+4
            if (c + 2 < 64) w1_u(bufA, c + 2);
            if (c + 4 < 64) w1_load(bufA, c + 4);
            w1_fly(c);
            block_sync();
        }
        w1_fly(63);
    }
}

extern "C" void kernel_launch(void* const* d_in, const int* in_sizes, int n_in,
                              void* d_out, int out_size, void* d_ws, size_t ws_size,
                              hipStream_t stream) {
    const float* x   = (const float*)d_in[0];
    const float* Wih = (const float*)d_in[1];
    const float* Whh = (const float*)d_in[2];
    const float* bih = (const float*)d_in[3];
    const float* bhh = (const float*)d_in[4];
    const float* Wfc = (const float*)d_in[5];
    const float* bfc = (const float*)d_in[6];
    float* out = (float*)d_out;

    // 1024 blocks x 128 thr (2 waves: serial + helper), 8 chains/block.
    // 2048 waves total = 2 waves/SIMD -> TLP covers serial-wave stalls.
    rnn_kernel<<<dim3(B_TOTAL / 8), dim3(128), 0, stream>>>(
        x, Wih, Whh, bih, bhh, Wfc, bfc, out);
}

// Round 6
// 203.341 us; speedup vs baseline: 1.1859x; 1.1335x over previous
//
#include <hip/hip_runtime.h>
#include <stdint.h>

// RNN: h_t = tanh(x_t W_ih^T + b_ih + b_hh + h_{t-1} W_hh^T)
// out[b,t] = W_fc . h_t + b_fc ;  hidden = h_T.  B=8192, T=512, I=H=7. fp32.
//
// R6: back to R3 topology (single self-sufficient wave, 8 lanes/chain, no
// LDS, no barriers) but with REAL prefetch: inline-asm global_load_dwordx4
// into "=v" registers + explicit s_waitcnt vmcnt(N) asm with "+v" operands.
// R4/R5 proved the compiler sinks HIP-level prefetch (VGPR 84 both rounds);
// asm defs cannot be sunk. Needed buffer is always the OLDEST outstanding
// VMEM, so vmcnt(14) (keep only the fresh reload in flight) is safe.
// #pragma unroll 1 on the outer loop keeps the hot body ~5 KB (I$-safe).

#define B_TOTAL 8192
#define T_STEPS 512

#define DPP_QUAD0 0x00        // quad_perm [0,0,0,0]
#define DPP_QUAD1 0x55        // quad_perm [1,1,1,1]
#define DPP_QUAD2 0xAA        // quad_perm [2,2,2,2]
#define DPP_QUAD3 0xFF        // quad_perm [3,3,3,3]
#define DPP_XOR1  0xB1        // quad_perm [1,0,3,2]
#define DPP_XOR2  0x4E        // quad_perm [2,3,0,1]
#define DPP_HM    0x141       // row_half_mirror

template <int CTRL>
__device__ __forceinline__ float dpp_mov(float v) {
    int s = __float_as_int(v);
    return __int_as_float(__builtin_amdgcn_update_dpp(s, s, CTRL, 0xF, 0xF, true));
}

__device__ __forceinline__ float tanh_fast(float a) {
    float e = __builtin_amdgcn_exp2f(a * 2.8853900817779268f);
    float r = __builtin_amdgcn_rcpf(e + 1.0f);
    return __builtin_fmaf(-2.0f, r, 1.0f);
}

typedef float v4f __attribute__((ext_vector_type(4)));

struct XChunk { v4f v[14]; };   // 8 steps * 7 floats = 56 floats = 224 B

// Issue 14 async 16B loads; results land in the asm-def'd VGPRs at vmcnt.
__device__ __forceinline__ void chunk_issue(XChunk& ch, const float* base) {
    #pragma unroll
    for (int i = 0; i < 14; ++i)
        asm volatile("global_load_dwordx4 %0, %1, off offset:%2"
                     : "=v"(ch.v[i]) : "v"(base), "i"(16 * i));
}

// Wait until at most N VMEM ops outstanding; "+v" operands force ordering
// (asm is a use+def of every buffer register -> compiler cannot hoist uses).
#define CHUNK_WAIT(ch, N)                                                     \
    asm volatile("s_waitcnt vmcnt(" #N ")"                                    \
        : "+v"((ch).v[0]), "+v"((ch).v[1]), "+v"((ch).v[2]), "+v"((ch).v[3]), \
          "+v"((ch).v[4]), "+v"((ch).v[5]), "+v"((ch).v[6]), "+v"((ch).v[7]), \
          "+v"((ch).v[8]), "+v"((ch).v[9]), "+v"((ch).v[10]),                 \
          "+v"((ch).v[11]), "+v"((ch).v[12]), "+v"((ch).v[13]))

__global__ __launch_bounds__(256, 1) void rnn_kernel(
    const float* __restrict__ x,    // [B, T, I]
    const float* __restrict__ Wih,  // [H, I]
    const float* __restrict__ Whh,  // [H, H]
    const float* __restrict__ bih,  // [H]
    const float* __restrict__ bhh,  // [H]
    const float* __restrict__ Wfc,  // [1, H]
    const float* __restrict__ bfc,  // [1]
    float* __restrict__ out)        // [B*T] out, then [B*H] hidden
{
    const int tid  = threadIdx.x;
    const int k    = tid & 7;                 // h-row (7 = dummy)
    const int b    = blockIdx.x * 32 + (tid >> 3);
    const int quad = (tid >> 2) & 1;

    // ---- weights first (compiler loads + its own waitcnts happen here,
    // BEFORE any asm prefetch is outstanding) ----
    float wih[7];
    float wa[4], wb[4];
    float bias = 0.0f, wfc_own = 0.0f;
    {
        float whh_row[8];
        #pragma unroll
        for (int i = 0; i < 8; ++i) whh_row[i] = 0.0f;
        if (k < 7) {
            #pragma unroll
            for (int i = 0; i < 7; ++i) {
                wih[i] = Wih[k * 7 + i];
                whh_row[i] = Whh[k * 7 + i];
            }
            bias = bih[k] + bhh[k];
            wfc_own = Wfc[k];
        } else {
            #pragma unroll
            for (int i = 0; i < 7; ++i) wih[i] = 0.0f;
        }
        #pragma unroll
        for (int j = 0; j < 4; ++j) {
            wa[j] = quad ? whh_row[4 + j] : whh_row[j];
            wb[j] = quad ? whh_row[j]     : whh_row[4 + j];
        }
    }
    const float bfcv = bfc[0];

    const float* xrow = x + (size_t)b * (T_STEPS * 7);   // 3584 floats
    float* outp = out + (size_t)b * T_STEPS;

    float a0 = 0.f, a1 = 0.f, a2 = 0.f, a3 = 0.f;
    float b0 = 0.f, b1 = 0.f, b2 = 0.f, b3 = 0.f;

    XChunk A, B;
    chunk_issue(A, xrow);            // chunk 0
    chunk_issue(B, xrow + 56);       // chunk 1

    // Process one ready 8-step chunk; optionally reissue its buffer with the
    // chunk-ahead reload right after the u-extraction consumes it.
    auto do_chunk = [&](XChunk& buf, int c, const float* reload) {
        float u[8];
        {
            float xv[56];
            #pragma unroll
            for (int i = 0; i < 14; ++i) {
                xv[4 * i + 0] = buf.v[i].x; xv[4 * i + 1] = buf.v[i].y;
                xv[4 * i + 2] = buf.v[i].z; xv[4 * i + 3] = buf.v[i].w;
            }
            #pragma unroll
            for (int s = 0; s < 8; ++s) {
                const float* xs = &xv[s * 7];
                float p01 = __builtin_fmaf(wih[1], xs[1], wih[0] * xs[0]);
                float p23 = __builtin_fmaf(wih[3], xs[3], wih[2] * xs[2]);
                float p45 = __builtin_fmaf(wih[5], xs[5], wih[4] * xs[4]);
                float p6b = __builtin_fmaf(wih[6], xs[6], bias);
                u[s] = (p01 + p23) + (p45 + p6b);
            }
        }
        if (reload) chunk_issue(buf, reload);   // in flight across the 8 steps
        // Serial recurrence (b-values consumed last in the tree)
        float hs[8];
        #pragma unroll
        for (int s = 0; s < 8; ++s) {
            float p0 = __builtin_fmaf(wa[0], a0, u[s]);
            float p1 = __builtin_fmaf(wa[2], a2, wa[1] * a1);
            float p2 = __builtin_fmaf(wb[0], b0, wa[3] * a3);
            float p3 = __builtin_fmaf(wb[2], b2, wb[1] * b1);
            float p4 = wb[3] * b3;
            float acc = (p0 + p1) + (p2 + (p3 + p4));
            float hk = tanh_fast(acc);
            hs[s] = hk;
            a0 = dpp_mov<DPP_QUAD0>(hk);
            a1 = dpp_mov<DPP_QUAD1>(hk);
            a2 = dpp_mov<DPP_QUAD2>(hk);
            a3 = dpp_mov<DPP_QUAD3>(hk);
            b0 = dpp_mov<DPP_HM>(a0);
            b1 = dpp_mov<DPP_HM>(a1);
            b2 = dpp_mov<DPP_HM>(a2);
            b3 = dpp_mov<DPP_HM>(a3);
        }
        // Out-projection butterfly (ILP filler)
        float o[8];
        #pragma unroll
        for (int s = 0; s < 8; ++s) {
            float v = wfc_own * hs[s];
            v += dpp_mov<DPP_XOR1>(v);
            v += dpp_mov<DPP_XOR2>(v);
            v += dpp_mov<DPP_HM>(v);
            o[s] = v + bfcv;
        }
        if (k == 7) {
            *(float4*)(outp + c * 8 + 0) = make_float4(o[0], o[1], o[2], o[3]);
            *(float4*)(outp + c * 8 + 4) = make_float4(o[4], o[5], o[6], o[7]);
        }
    };

    // Steady loop: chunks 0..61; reloads c+2 (<=62) and c+3 (<=63) always valid.
    #pragma unroll 1
    for (int c = 0; c < 62; c += 2) {
        CHUNK_WAIT(A, 14);                         // A(c) is oldest -> drained
        do_chunk(A, c, xrow + (c + 2) * 56);
        CHUNK_WAIT(B, 14);                         // B(c+1) oldest -> drained
        do_chunk(B, c + 1, xrow + (c + 3) * 56);
    }
    // Epilogue: chunks 62 (A) and 63 (B), no reloads.
    CHUNK_WAIT(A, 14);
    do_chunk(A, 62, nullptr);
    CHUNK_WAIT(B, 0);
    do_chunk(B, 63, nullptr);

    // hidden h_T: lane k's own value is a_{k&3} (both quads)
    if (k < 7) {
        int kk = k & 3;
        float hv = (kk == 0) ? a0 : (kk == 1) ? a1 : (kk == 2) ? a2 : a3;
        out[(size_t)B_TOTAL * T_STEPS + (size_t)b * 7 + k] = hv;
    }
}

extern "C" void kernel_launch(void* const* d_in, const int* in_sizes, int n_in,
                              void* d_out, int out_size, void* d_ws, size_t ws_size,
                              hipStream_t stream) {
    const float* x   = (const float*)d_in[0];
    const float* Wih = (const float*)d_in[1];
    const float* Whh = (const float*)d_in[2];
    const float* bih = (const float*)d_in[3];
    const float* bhh = (const float*)d_in[4];
    const float* Wfc = (const float*)d_in[5];
    const float* bfc = (const float*)d_in[6];
    float* out = (float*)d_out;

    // 8192 chains * 8 lanes = 65536 threads; 256/block -> 256 blocks (1/CU),
    // 4 waves/block spread over the 4 SIMDs -> 1 wave/SIMD chip-wide.
    rnn_kernel<<<dim3(B_TOTAL / 32), dim3(256), 0, stream>>>(
        x, Wih, Whh, bih, bhh, Wfc, bfc, out);
}